// Round 1
// baseline (478.916 us; speedup 1.0000x reference)
//
#include <hip/hip_runtime.h>

#define DD 256
#define RR 32
#define HH 64
#define CC 64
#define PB 96
#define NBB 32
#define HSTR 260   // h row stride (floats): 16B-aligned, breaks power-of-2 banks
#define WSTR 260
#define LSTR 33    // hlow/A row stride

__global__ __launch_bounds__(256, 1)
void hydra_kernel(const float* __restrict__ x,
                  const float* __restrict__ ln_g, const float* __restrict__ ln_b,
                  const float* __restrict__ Wd, const float* __restrict__ bd,
                  const float* __restrict__ Wq, const float* __restrict__ Wk,
                  const float* __restrict__ Wv, const float* __restrict__ Wg,
                  const float* __restrict__ bg,
                  const float* __restrict__ Wu, const float* __restrict__ bu,
                  const float* __restrict__ W1, const float* __restrict__ b1,
                  const float* __restrict__ W2, const float* __restrict__ b2,
                  float* __restrict__ out)
{
    __shared__ float h[CC][HSTR];          // raw h tile (kept through the end)
    __shared__ float wbig[RR * WSTR];      // staged weights (Wd~, then Wq..Wg, then Wu)
    __shared__ float hlow[CC * LSTR];
    __shared__ float Abuf[CC * LSTR];      // K*V products, then (Q*gf*gate_c)
    __shared__ float cv_s[DD];
    __shared__ float gate_s[DD];
    __shared__ float mu_s[CC], rstd_s[CC];
    __shared__ float ln_a[RR], ln_bv[RR];
    __shared__ float mlp_part[4 * HH];
    __shared__ float hid_s[HH];
    __shared__ float gf_s[RR];

    const int t    = threadIdx.x;
    const int bp   = blockIdx.x;
    const int b    = bp / PB;
    const int p    = bp - b * PB;
    const int lane = t & 63;
    const int wave = t >> 6;

    // h[c][d] = x[(b*CC + c)*PB + p][d]
    const size_t rowbase = (size_t)(b * CC) * PB * DD + (size_t)p * DD;

    // ---- S0: load h tile (each wave: 16 rows, 64 lanes = one float4/row) ----
    for (int i = 0; i < 16; ++i) {
        const int c = wave * 16 + i;
        const float4 v = *(const float4*)(x + rowbase + (size_t)c * (PB * DD) + lane * 4);
        *(float4*)&h[c][lane * 4] = v;
    }
    __syncthreads();

    // ---- S1: LN stats per row + channel variance per column ----
    for (int i = 0; i < 16; ++i) {
        const int c = wave * 16 + i;
        float s1 = 0.f, s2 = 0.f;
        #pragma unroll
        for (int k = 0; k < 4; ++k) {
            const float v = h[c][lane + 64 * k];
            s1 += v; s2 += v * v;
        }
        #pragma unroll
        for (int off = 32; off; off >>= 1) {
            s1 += __shfl_xor(s1, off, 64);
            s2 += __shfl_xor(s2, off, 64);
        }
        if (lane == 0) {
            const float mu  = s1 * (1.f / 256.f);
            const float var = s2 * (1.f / 256.f) - mu * mu;   // biased (LN)
            mu_s[c]   = mu;
            rstd_s[c] = rsqrtf(var + 1e-5f);
        }
    }
    {   // chan_var over c (ddof=1), d = t
        float s1 = 0.f, s2 = 0.f;
        for (int c = 0; c < CC; ++c) {
            const float v = h[c][t];
            s1 += v; s2 += v * v;
        }
        const float mean = s1 * (1.f / 64.f);
        cv_s[t] = (s2 - s1 * mean) * (1.f / 63.f);
    }
    __syncthreads();

    // ---- S2: stage Wt = gamma*Wd (transposed [r][d]); LN-fold vectors; MLP part1 ----
    for (int i = 0; i < 32; ++i) {
        const int idx = i * 256 + t;        // = d*32 + r
        const int d = idx >> 5, r = idx & 31;
        wbig[r * WSTR + d] = ln_g[d] * Wd[idx];
    }
    if (t < RR) {
        float s2 = 0.f, s3 = 0.f;
        for (int d = 0; d < DD; ++d) {
            const float w = Wd[d * RR + t];
            s2 += ln_g[d] * w;
            s3 += ln_b[d] * w;
        }
        ln_a[t]  = s2;
        ln_bv[t] = s3 + bd[t];
    }
    {   // cv @ W1 partials: j = t&63 output, qc = t>>6 chunk of d
        const int j = t & 63, qc = t >> 6;
        float s = 0.f;
        for (int d = 0; d < 64; ++d)
            s += cv_s[qc * 64 + d] * W1[(qc * 64 + d) * HH + j];
        mlp_part[qc * HH + j] = s;
    }
    __syncthreads();

    // ---- S3: h_low = LN(h) @ Wd + bd  (folded);  MLP hidden finalize ----
    if (t < HH) {
        const float s = mlp_part[t] + mlp_part[HH + t] + mlp_part[2 * HH + t]
                      + mlp_part[3 * HH + t] + b1[t];
        hid_s[t] = 0.5f * s * (1.f + erff(s * 0.70710678118654752f));  // exact gelu
    }
    {
        const int c = t & 63, rg = t >> 6;
        float acc[8];
        #pragma unroll
        for (int j = 0; j < 8; ++j) acc[j] = 0.f;
        for (int d = 0; d < DD; d += 4) {
            const float4 hv = *(const float4*)&h[c][d];
            #pragma unroll
            for (int j = 0; j < 8; ++j) {
                const float4 wv = *(const float4*)&wbig[(rg * 8 + j) * WSTR + d];
                acc[j] += hv.x * wv.x + hv.y * wv.y + hv.z * wv.z + hv.w * wv.w;
            }
        }
        const float rs = rstd_s[c], mu = mu_s[c];
        #pragma unroll
        for (int j = 0; j < 8; ++j) {
            const int r = rg * 8 + j;
            hlow[c * LSTR + r] = rs * acc[j] - rs * mu * ln_a[r] + ln_bv[r];
        }
    }
    __syncthreads();

    // ---- S4: stage Wq/Wk/Wv/Wg; gate logits from hidden ----
    {
        const float* Wm[4] = {Wq, Wk, Wv, Wg};
        #pragma unroll
        for (int m = 0; m < 4; ++m)
            for (int i = 0; i < 4; ++i) {
                const int idx = i * 256 + t;   // = k*32 + r
                const int k = idx >> 5, r = idx & 31;
                wbig[m * RR * LSTR + k * LSTR + r] = Wm[m][idx];
            }
        float s = 0.f;
        for (int j = 0; j < HH; ++j)
            s += hid_s[j] * W2[j * DD + t];
        s += b2[t];
        gate_s[t] = 1.f / (1.f + __expf(-s) * 0.f + expf(-s));  // keep exact expf
    }
    __syncthreads();

    // ---- S5: Q,K,V,G dots; l2norm Q,K; K*V -> Abuf ----
    float qv[8], gv[8];
    const int c3 = t >> 2, rg3 = t & 3;
    {
        float kv[8], vv[8];
        #pragma unroll
        for (int j = 0; j < 8; ++j) { qv[j] = 0.f; kv[j] = 0.f; vv[j] = 0.f; gv[j] = 0.f; }
        for (int k = 0; k < RR; ++k) {
            const float hl = hlow[c3 * LSTR + k];
            #pragma unroll
            for (int j = 0; j < 8; ++j) {
                const int r = rg3 * 8 + j;
                qv[j] += hl * wbig[0 * RR * LSTR + k * LSTR + r];
                kv[j] += hl * wbig[1 * RR * LSTR + k * LSTR + r];
                vv[j] += hl * wbig[2 * RR * LSTR + k * LSTR + r];
                gv[j] += hl * wbig[3 * RR * LSTR + k * LSTR + r];
            }
        }
        float ssq = 0.f, ssk = 0.f;
        #pragma unroll
        for (int j = 0; j < 8; ++j) { ssq += qv[j] * qv[j]; ssk += kv[j] * kv[j]; }
        ssq += __shfl_xor(ssq, 1, 64); ssq += __shfl_xor(ssq, 2, 64);
        ssk += __shfl_xor(ssk, 1, 64); ssk += __shfl_xor(ssk, 2, 64);
        const float sq = 1.f / fmaxf(sqrtf(ssq), 1e-12f);
        const float sk = 1.f / fmaxf(sqrtf(ssk), 1e-12f);
        #pragma unroll
        for (int j = 0; j < 8; ++j) {
            const int r = rg3 * 8 + j;
            qv[j] *= sq;
            Abuf[c3 * LSTR + r] = (kv[j] * sk) * vv[j];
            gv[j] = 1.f / (1.f + expf(-(gv[j] + bg[r])));
        }
    }
    __syncthreads();

    // ---- S6: global feature = sum_c K*V ----
    if (t < RR) {
        float s = 0.f;
        for (int c = 0; c < CC; ++c) s += Abuf[c * LSTR + t];
        gf_s[t] = s;
    }
    __syncthreads();

    // ---- S7: A = Qn * gf * gate_c ; stage Wu [r][d] ----
    #pragma unroll
    for (int j = 0; j < 8; ++j) {
        const int r = rg3 * 8 + j;
        Abuf[c3 * LSTR + r] = qv[j] * gf_s[r] * gv[j];
    }
    for (int i = 0; i < 32; ++i) {
        const int idx = i * 256 + t;      // = r*256 + d
        const int r = idx >> 8, d = idx & 255;
        wbig[r * WSTR + d] = Wu[idx];
    }
    __syncthreads();

    // ---- S8: mixed = A @ Wu + bu ; out = h + gate*mixed ----
    {
        const int c = t >> 2, q = t & 3;
        float4 macc[16];
        #pragma unroll
        for (int k = 0; k < 16; ++k) macc[k] = make_float4(0.f, 0.f, 0.f, 0.f);
        for (int r = 0; r < RR; ++r) {
            const float a = Abuf[c * LSTR + r];
            #pragma unroll
            for (int k = 0; k < 16; ++k) {
                const int d = 4 * (q + 4 * k);
                const float4 wv = *(const float4*)&wbig[r * WSTR + d];
                macc[k].x += a * wv.x; macc[k].y += a * wv.y;
                macc[k].z += a * wv.z; macc[k].w += a * wv.w;
            }
        }
        float* orow = out + rowbase + (size_t)c * (PB * DD);
        #pragma unroll
        for (int k = 0; k < 16; ++k) {
            const int d = 4 * (q + 4 * k);
            const float4 hv  = *(const float4*)&h[c][d];
            const float4 g4  = *(const float4*)&gate_s[d];
            const float4 bu4 = *(const float4*)(bu + d);
            float4 o;
            o.x = hv.x + g4.x * (macc[k].x + bu4.x);
            o.y = hv.y + g4.y * (macc[k].y + bu4.y);
            o.z = hv.z + g4.z * (macc[k].z + bu4.z);
            o.w = hv.w + g4.w * (macc[k].w + bu4.w);
            *(float4*)(orow + d) = o;
        }
    }
}

extern "C" void kernel_launch(void* const* d_in, const int* in_sizes, int n_in,
                              void* d_out, int out_size, void* d_ws, size_t ws_size,
                              hipStream_t stream) {
    (void)in_sizes; (void)n_in; (void)out_size; (void)d_ws; (void)ws_size;
    const float* x    = (const float*)d_in[0];
    const float* ln_g = (const float*)d_in[1];
    const float* ln_b = (const float*)d_in[2];
    const float* Wd   = (const float*)d_in[3];
    const float* bd   = (const float*)d_in[4];
    const float* Wq   = (const float*)d_in[5];
    const float* Wk   = (const float*)d_in[6];
    const float* Wv   = (const float*)d_in[7];
    const float* Wg   = (const float*)d_in[8];
    const float* bg   = (const float*)d_in[9];
    const float* Wu   = (const float*)d_in[10];
    const float* bu   = (const float*)d_in[11];
    const float* W1   = (const float*)d_in[12];
    const float* b1   = (const float*)d_in[13];
    const float* W2   = (const float*)d_in[14];
    const float* b2   = (const float*)d_in[15];
    float* out = (float*)d_out;

    hydra_kernel<<<dim3(NBB * PB), dim3(256), 0, stream>>>(
        x, ln_g, ln_b, Wd, bd, Wq, Wk, Wv, Wg, bg, Wu, bu, W1, b1, W2, b2, out);
}

// Round 3
// 364.402 us; speedup vs baseline: 1.3143x; 1.3143x over previous
//
#include <hip/hip_runtime.h>

#define DD 256
#define RR 32
#define HH 64
#define CC 64
#define PB 96
#define NBB 32
#define HSTR 260   // h row stride (floats)
#define WSTR 260   // big weight stride (gammaWd / Wu, [r][d])
#define QSTR 36    // QKVG transposed row stride [r][k]
#define QMAT 1152  // 32*36 per matrix
#define ASTR 36    // hlow/Abuf row stride
#define NT 1024

__global__ __launch_bounds__(NT, 1)
void hydra_kernel(const float* __restrict__ x,
                  const float* __restrict__ ln_g, const float* __restrict__ ln_b,
                  const float* __restrict__ Wd, const float* __restrict__ bd,
                  const float* __restrict__ Wq, const float* __restrict__ Wk,
                  const float* __restrict__ Wv, const float* __restrict__ Wg,
                  const float* __restrict__ bg,
                  const float* __restrict__ Wu, const float* __restrict__ bu,
                  const float* __restrict__ W1, const float* __restrict__ b1,
                  const float* __restrict__ W2, const float* __restrict__ b2,
                  float* __restrict__ out)
{
    __shared__ float h[CC][HSTR];      // raw h tile, kept to the end
    __shared__ float wbig[RR * WSTR];  // gammaWd -> QKVG(transposed) -> Wu
    __shared__ float hlow[CC * ASTR];
    __shared__ float Abuf[CC * ASTR];
    __shared__ float red[2560];        // generic reduction scratch
    __shared__ float cv_s[DD], gate_s[DD];
    __shared__ float mu_s[CC], rstd_s[CC];
    __shared__ float ln_a[RR], ln_bv[RR];
    __shared__ float hid_s[HH], gf_s[RR];

    const int t    = threadIdx.x;
    const int lane = t & 63;
    const int wave = t >> 6;
    const int bp   = blockIdx.x;
    const int b    = bp / PB;
    const int p    = bp - b * PB;

    const size_t rowbase = (size_t)(b * CC) * PB * DD + (size_t)p * DD;

    // ---- S0: load h tile. wave w loads rows 4w..4w+3, one row per float4-sweep ----
    #pragma unroll
    for (int i = 0; i < 4; ++i) {
        const int c = wave * 4 + i;
        const float4 v = *(const float4*)(x + rowbase + (size_t)c * (PB * DD) + lane * 4);
        *(float4*)&h[c][lane * 4] = v;
    }
    __syncthreads();

    // ---- S1: LN row stats; chan_var partials; ln-fold partials ----
    #pragma unroll
    for (int i = 0; i < 4; ++i) {
        const int c = wave * 4 + i;
        float s1 = 0.f, s2 = 0.f;
        #pragma unroll
        for (int k = 0; k < 4; ++k) {
            const float v = h[c][lane + 64 * k];
            s1 += v; s2 += v * v;
        }
        #pragma unroll
        for (int off = 32; off; off >>= 1) {
            s1 += __shfl_xor(s1, off, 64);
            s2 += __shfl_xor(s2, off, 64);
        }
        if (lane == 0) {
            const float mu  = s1 * (1.f / 256.f);
            const float var = s2 * (1.f / 256.f) - mu * mu;  // biased (LN)
            mu_s[c]   = mu;
            rstd_s[c] = rsqrtf(var + 1e-5f);
        }
    }
    {   // chan_var partials: d = t&255, qc = t>>8 sums 16 rows
        const int d = t & 255, qc = t >> 8;
        float s1 = 0.f, s2 = 0.f;
        #pragma unroll
        for (int i = 0; i < 16; ++i) {
            const float v = h[qc * 16 + i][d];
            s1 += v; s2 += v * v;
        }
        red[qc * 256 + d]        = s1;
        red[1024 + qc * 256 + d] = s2;
    }
    if (t < 256) {  // ln-fold partials: r = t&31, ch = t>>5 over 32 d's
        const int r = t & 31, ch = t >> 5;
        float sa = 0.f, sb = 0.f;
        for (int i = 0; i < 32; ++i) {
            const int d = ch * 32 + i;
            const float w = Wd[d * RR + r];
            sa += ln_g[d] * w;
            sb += ln_b[d] * w;
        }
        red[2048 + ch * 32 + r] = sa;
        red[2304 + ch * 32 + r] = sb;
    }
    __syncthreads();

    // ---- S2: finalize cv_s, ln_a/ln_bv; stage gamma*Wd transposed [r][d] ----
    if (t < 256) {
        const float S1 = red[t] + red[256 + t] + red[512 + t] + red[768 + t];
        const float S2 = red[1024 + t] + red[1280 + t] + red[1536 + t] + red[1792 + t];
        cv_s[t] = (S2 - S1 * S1 * (1.f / 64.f)) * (1.f / 63.f);  // ddof=1
    }
    if (t < RR) {
        float sa = 0.f, sb = 0.f;
        #pragma unroll
        for (int ch = 0; ch < 8; ++ch) { sa += red[2048 + ch * 32 + t]; sb += red[2304 + ch * 32 + t]; }
        ln_a[t]  = sa;
        ln_bv[t] = sb + bd[t];
    }
    #pragma unroll
    for (int i = 0; i < 8; ++i) {
        const int idx = i * NT + t;          // = d*32 + r
        const int d = idx >> 5, r = idx & 31;
        wbig[r * WSTR + d] = ln_g[d] * Wd[idx];
    }
    __syncthreads();

    // ---- S3: h_low = LN(h)@Wd + bd (folded); cv@W1 partials ----
    {
        const int c = lane;                  // wave rg computes r = 2*wave, 2*wave+1
        const int r0 = wave * 2, r1 = r0 + 1;
        float a0 = 0.f, a1 = 0.f;
        for (int d = 0; d < DD; d += 4) {
            const float4 hv = *(const float4*)&h[c][d];
            const float4 w0 = *(const float4*)&wbig[r0 * WSTR + d];
            const float4 w1 = *(const float4*)&wbig[r1 * WSTR + d];
            a0 += hv.x * w0.x + hv.y * w0.y + hv.z * w0.z + hv.w * w0.w;
            a1 += hv.x * w1.x + hv.y * w1.y + hv.z * w1.z + hv.w * w1.w;
        }
        const float rs = rstd_s[c], mu = mu_s[c];
        hlow[c * ASTR + r0] = rs * a0 - rs * mu * ln_a[r0] + ln_bv[r0];
        hlow[c * ASTR + r1] = rs * a1 - rs * mu * ln_a[r1] + ln_bv[r1];
    }
    {   // cv@W1 partials: j = t&63, qc = t>>6 over 16 d's
        const int j = t & 63, qc = t >> 6;
        float s = 0.f;
        #pragma unroll
        for (int i = 0; i < 16; ++i)
            s += cv_s[qc * 16 + i] * W1[(qc * 16 + i) * HH + j];
        red[qc * 64 + j] = s;
    }
    __syncthreads();

    // ---- S4: stage Wq/Wk/Wv/Wg transposed [r][k] stride 36; finalize hidden (gelu) ----
    {
        const int k = t >> 5, r = t & 31;
        const int woff = r * QSTR + k;
        wbig[0 * QMAT + woff] = Wq[t];
        wbig[1 * QMAT + woff] = Wk[t];
        wbig[2 * QMAT + woff] = Wv[t];
        wbig[3 * QMAT + woff] = Wg[t];
    }
    if (t < HH) {
        float s = b1[t];
        #pragma unroll
        for (int qc = 0; qc < 16; ++qc) s += red[qc * 64 + t];
        hid_s[t] = 0.5f * s * (1.f + erff(s * 0.70710678118654752f));
    }
    __syncthreads();

    // ---- S5: QKVG dots (c3 = t>>4 row, rg3 = t&15 -> r pair); gate@W2 partials ----
    const int c3 = t >> 4, rg3 = t & 15;
    const int r0 = rg3 * 2, r1 = r0 + 1;
    float q0, q1, g0, g1;
    {
        float k0 = 0.f, k1 = 0.f, v0 = 0.f, v1 = 0.f;
        q0 = q1 = g0 = g1 = 0.f;
        for (int k = 0; k < RR; k += 4) {
            const float4 hl  = *(const float4*)&hlow[c3 * ASTR + k];
            const float4 wq0 = *(const float4*)&wbig[0 * QMAT + r0 * QSTR + k];
            const float4 wq1 = *(const float4*)&wbig[0 * QMAT + r1 * QSTR + k];
            const float4 wk0 = *(const float4*)&wbig[1 * QMAT + r0 * QSTR + k];
            const float4 wk1 = *(const float4*)&wbig[1 * QMAT + r1 * QSTR + k];
            const float4 wv0 = *(const float4*)&wbig[2 * QMAT + r0 * QSTR + k];
            const float4 wv1 = *(const float4*)&wbig[2 * QMAT + r1 * QSTR + k];
            const float4 wg0 = *(const float4*)&wbig[3 * QMAT + r0 * QSTR + k];
            const float4 wg1 = *(const float4*)&wbig[3 * QMAT + r1 * QSTR + k];
            q0 += hl.x * wq0.x + hl.y * wq0.y + hl.z * wq0.z + hl.w * wq0.w;
            q1 += hl.x * wq1.x + hl.y * wq1.y + hl.z * wq1.z + hl.w * wq1.w;
            k0 += hl.x * wk0.x + hl.y * wk0.y + hl.z * wk0.z + hl.w * wk0.w;
            k1 += hl.x * wk1.x + hl.y * wk1.y + hl.z * wk1.z + hl.w * wk1.w;
            v0 += hl.x * wv0.x + hl.y * wv0.y + hl.z * wv0.z + hl.w * wv0.w;
            v1 += hl.x * wv1.x + hl.y * wv1.y + hl.z * wv1.z + hl.w * wv1.w;
            g0 += hl.x * wg0.x + hl.y * wg0.y + hl.z * wg0.z + hl.w * wg0.w;
            g1 += hl.x * wg1.x + hl.y * wg1.y + hl.z * wg1.z + hl.w * wg1.w;
        }
        // l2norm across the row's 16 lanes (each holds 2 r's)
        float ssq = q0 * q0 + q1 * q1, ssk = k0 * k0 + k1 * k1;
        #pragma unroll
        for (int off = 1; off < 16; off <<= 1) {
            ssq += __shfl_xor(ssq, off, 64);
            ssk += __shfl_xor(ssk, off, 64);
        }
        const float sq = 1.f / fmaxf(sqrtf(ssq), 1e-12f);
        const float sk = 1.f / fmaxf(sqrtf(ssk), 1e-12f);
        q0 *= sq; q1 *= sq;
        g0 = 1.f / (1.f + expf(-(g0 + bg[r0])));
        g1 = 1.f / (1.f + expf(-(g1 + bg[r1])));
        // K*V products; wave-level sum over the wave's 4 rows -> per-wave gf partial
        float p0 = (k0 * sk) * v0, p1 = (k1 * sk) * v1;
        p0 += __shfl_xor(p0, 16, 64); p0 += __shfl_xor(p0, 32, 64);
        p1 += __shfl_xor(p1, 16, 64); p1 += __shfl_xor(p1, 32, 64);
        if ((lane >> 4) == 0) {
            red[1024 + wave * 32 + r0] = p0;
            red[1024 + wave * 32 + r1] = p1;
        }
    }
    {   // gate logits partials: d = t&255, ch = t>>8 over 16 hidden
        const int d = t & 255, ch = t >> 8;
        float s = 0.f;
        #pragma unroll
        for (int i = 0; i < 16; ++i)
            s += hid_s[ch * 16 + i] * W2[(ch * 16 + i) * DD + d];
        red[ch * 256 + d] = s;
    }
    __syncthreads();

    // ---- S6: finalize gate_s; finalize gf ----
    if (t < 256) {
        const float s = red[t] + red[256 + t] + red[512 + t] + red[768 + t] + b2[t];
        gate_s[t] = 1.f / (1.f + expf(-s));
    }
    if (t >= 256 && t < 256 + RR) {
        const int r = t - 256;
        float s = 0.f;
        #pragma unroll
        for (int w = 0; w < 16; ++w) s += red[1024 + w * 32 + r];
        gf_s[r] = s;
    }
    __syncthreads();

    // ---- S7: A = Qn*gf*gate_c; stage Wu [r][d] ----
    Abuf[c3 * ASTR + r0] = q0 * gf_s[r0] * g0;
    Abuf[c3 * ASTR + r1] = q1 * gf_s[r1] * g1;
    #pragma unroll
    for (int i = 0; i < 8; ++i) {
        const int idx = i * NT + t;          // = r*256 + d
        const int r = idx >> 8, d = idx & 255;
        wbig[r * WSTR + d] = Wu[idx];
    }
    __syncthreads();

    // ---- S8: mixed = A@Wu + bu; out = h + gate*mixed ----
    {
        const int c = t >> 4, q = t & 15;
        float4 macc[4];
        #pragma unroll
        for (int k = 0; k < 4; ++k) macc[k] = make_float4(0.f, 0.f, 0.f, 0.f);
        for (int r = 0; r < RR; ++r) {
            const float a = Abuf[c * ASTR + r];
            #pragma unroll
            for (int k = 0; k < 4; ++k) {
                const int d = 4 * q + 64 * k;
                const float4 wv = *(const float4*)&wbig[r * WSTR + d];
                macc[k].x += a * wv.x; macc[k].y += a * wv.y;
                macc[k].z += a * wv.z; macc[k].w += a * wv.w;
            }
        }
        float* orow = out + rowbase + (size_t)c * (PB * DD);
        #pragma unroll
        for (int k = 0; k < 4; ++k) {
            const int d = 4 * q + 64 * k;
            const float4 hv  = *(const float4*)&h[c][d];
            const float4 g4  = *(const float4*)&gate_s[d];
            const float4 bu4 = *(const float4*)(bu + d);
            float4 o;
            o.x = hv.x + g4.x * (macc[k].x + bu4.x);
            o.y = hv.y + g4.y * (macc[k].y + bu4.y);
            o.z = hv.z + g4.z * (macc[k].z + bu4.z);
            o.w = hv.w + g4.w * (macc[k].w + bu4.w);
            *(float4*)(orow + d) = o;
        }
    }
}

extern "C" void kernel_launch(void* const* d_in, const int* in_sizes, int n_in,
                              void* d_out, int out_size, void* d_ws, size_t ws_size,
                              hipStream_t stream) {
    (void)in_sizes; (void)n_in; (void)out_size; (void)d_ws; (void)ws_size;
    const float* x    = (const float*)d_in[0];
    const float* ln_g = (const float*)d_in[1];
    const float* ln_b = (const float*)d_in[2];
    const float* Wd   = (const float*)d_in[3];
    const float* bd   = (const float*)d_in[4];
    const float* Wq   = (const float*)d_in[5];
    const float* Wk   = (const float*)d_in[6];
    const float* Wv   = (const float*)d_in[7];
    const float* Wg   = (const float*)d_in[8];
    const float* bg   = (const float*)d_in[9];
    const float* Wu   = (const float*)d_in[10];
    const float* bu   = (const float*)d_in[11];
    const float* W1   = (const float*)d_in[12];
    const float* b1   = (const float*)d_in[13];
    const float* W2   = (const float*)d_in[14];
    const float* b2   = (const float*)d_in[15];
    float* out = (float*)d_out;

    hydra_kernel<<<dim3(NBB * PB), dim3(NT), 0, stream>>>(
        x, ln_g, ln_b, Wd, bd, Wq, Wk, Wv, Wg, bg, Wu, bu, W1, b1, W2, b2, out);
}

// Round 4
// 172.713 us; speedup vs baseline: 2.7729x; 2.1099x over previous
//
#include <hip/hip_runtime.h>

#define DD 256
#define RR 32
#define CC 64
#define PB 96
#define NT 1024

typedef __attribute__((ext_vector_type(8))) short short8;
typedef __attribute__((ext_vector_type(4))) float f32x4;

__device__ __forceinline__ unsigned short f2b(float f) {
    union { float f; unsigned u; } v; v.f = f;
    unsigned r = v.u + 0x7fffu + ((v.u >> 16) & 1u);
    return (unsigned short)(r >> 16);
}
__device__ __forceinline__ float b2f(unsigned short s) {
    union { unsigned u; float f; } v; v.u = ((unsigned)s) << 16;
    return v.f;
}

// [64][256] bf16, 8-elem-block XOR swizzle by (row&7)
__device__ __forceinline__ int hidx(int c, int d) {
    return c * 256 + ((((d >> 3) ^ (c & 7)) << 3) | (d & 7));
}
// [*][32] bf16, 8-elem-block XOR swizzle by ((row>>1)&3)
__device__ __forceinline__ int nidx(int row, int k) {
    return row * 32 + ((((k >> 3) ^ ((row >> 1) & 3)) << 3) | (k & 7));
}

__global__ __launch_bounds__(NT, 8)
void hydra_kernel(const float* __restrict__ x,
                  const float* __restrict__ ln_g, const float* __restrict__ ln_b,
                  const float* __restrict__ Wd, const float* __restrict__ bd,
                  const float* __restrict__ Wq, const float* __restrict__ Wk,
                  const float* __restrict__ Wv, const float* __restrict__ Wg,
                  const float* __restrict__ bg,
                  const float* __restrict__ Wu, const float* __restrict__ bu,
                  const float* __restrict__ W1, const float* __restrict__ b1,
                  const float* __restrict__ W2, const float* __restrict__ b2,
                  float* __restrict__ out)
{
    __shared__ short hbf[CC * DD];          // 32 KB  h tile bf16, swizzled [64][256]
    __shared__ short wreg[RR * DD];         // 16 KB  gWd^T -> Wqkvg^T -> Wu^T
    __shared__ short lowbuf[CC * RR];       // 4 KB   hlow bf16 -> Abuf bf16 (swizzled [64][32])
    __shared__ short qgkv[2 * CC * RR];     // 8 KB   qg=[0..2048), kv=[2048..4096), linear [c][r]
    __shared__ float redA[2048];            // 8 KB   lnfold(P0-P1) | red3 W1 partials [8][64]@0, red1 gf [8][32]@512
    __shared__ float redB[1024];            // 4 KB   chanvar(P1-P2) | red2 W2 partials [4][256]
    __shared__ float mu_s[CC], rstd_s[CC];
    __shared__ float cv_s[DD], gate_s[DD];
    __shared__ float hid_s[64];
    __shared__ float ln_a[RR], ln_bv[RR];

    const int t    = threadIdx.x;
    const int lane = t & 63;
    const int w    = t >> 6;
    const int bp   = blockIdx.x;
    const int b    = bp / PB;
    const int p    = bp - b * PB;
    const size_t rowbase = (size_t)(b * CC) * PB * DD + (size_t)p * DD;

    // ================= P0: load x -> hbf (bf16, swizzled) + LN stats + stage gWd^T + lnfold partials
    #pragma unroll
    for (int i = 0; i < 4; ++i) {
        const int c = w * 4 + i;
        const float4 v = *(const float4*)(x + rowbase + (size_t)c * (PB * DD) + 4 * lane);
        float s1 = v.x + v.y + v.z + v.w;
        float s2 = v.x * v.x + v.y * v.y + v.z * v.z + v.w * v.w;
        #pragma unroll
        for (int off = 32; off; off >>= 1) {
            s1 += __shfl_xor(s1, off, 64);
            s2 += __shfl_xor(s2, off, 64);
        }
        if (lane == 0) {
            const float mu = s1 * (1.f / 256.f);
            mu_s[c]   = mu;
            rstd_s[c] = rsqrtf(s2 * (1.f / 256.f) - mu * mu + 1e-5f);
        }
        // write 4 bf16 as one b64
        ushort4 pk;
        pk.x = f2b(v.x); pk.y = f2b(v.y); pk.z = f2b(v.z); pk.w = f2b(v.w);
        *(ushort4*)&hbf[hidx(c, 4 * lane)] = pk;
    }
    {   // stage gWd^T[r][d] bf16 swizzled; accumulate lnfold partials
        const int r = t >> 5, dblk = t & 31;
        short8 vv;
        float sa = 0.f, sb = 0.f;
        #pragma unroll
        for (int j = 0; j < 8; ++j) {
            const int d = dblk * 8 + j;
            const float wd = Wd[d * RR + r];
            const float g  = ln_g[d];
            vv[j] = (short)f2b(g * wd);
            sa += g * wd;
            sb += ln_b[d] * wd;
        }
        *(short8*)&wreg[r * 256 + ((dblk ^ (r & 7)) << 3)] = vv;
        redA[r * 32 + dblk]        = sa;
        redA[1024 + r * 32 + dblk] = sb;
    }
    __syncthreads();

    // ================= P1: [w0-7] S3 MFMA (h @ gWd)   [w8-15] chan_var partials + lnfold finalize
    f32x4 s3acc = {0.f, 0.f, 0.f, 0.f};
    if (w < 8) {
        const int ct = w >> 1, rt = w & 1;
        const int arow = ct * 16 + (lane & 15);
        const int brow = rt * 16 + (lane & 15);
        const int ksub = lane >> 4;
        #pragma unroll
        for (int step = 0; step < 8; ++step) {
            const int kb = step * 4 + ksub;
            const short8 a  = *(const short8*)&hbf[arow * 256 + ((kb ^ (arow & 7)) << 3)];
            const short8 bf = *(const short8*)&wreg[brow * 256 + ((kb ^ (brow & 7)) << 3)];
            s3acc = __builtin_amdgcn_mfma_f32_16x16x32_bf16(a, bf, s3acc, 0, 0, 0);
        }
    } else {
        const int idx = t - 512;
        const int d = idx & 255, half = idx >> 8;
        float s1 = 0.f, s2 = 0.f;
        #pragma unroll 8
        for (int i = 0; i < 32; ++i) {
            const float v = b2f((unsigned short)hbf[hidx(half * 32 + i, d)]);
            s1 += v; s2 += v * v;
        }
        redB[half * 256 + d]       = s1;
        redB[512 + half * 256 + d] = s2;
        if (idx < 64) {
            const int r = idx & 31, which = idx >> 5;
            float s = 0.f;
            for (int g = 0; g < 32; ++g) s += redA[which * 1024 + r * 32 + g];
            if (which == 0) ln_a[r] = s;
            else            ln_bv[r] = s + bd[r];
        }
    }
    __syncthreads();

    // ================= P2: [w0-7] S3 epilogue -> lowbuf(hlow bf16)   [w8-15] stage Wqkvg^T ; cv finalize
    if (w < 8) {
        const int ct = w >> 1, rt = w & 1;
        const int col = rt * 16 + (lane & 15);
        const float la = ln_a[col], lb = ln_bv[col];
        #pragma unroll
        for (int i = 0; i < 4; ++i) {
            const int c = ct * 16 + (lane >> 4) * 4 + i;
            const float rs = rstd_s[c];
            const float hl = rs * s3acc[i] - rs * mu_s[c] * la + lb;
            lowbuf[nidx(c, col)] = (short)f2b(hl);
        }
    } else {
        const int slot = t - 512;
        const int m = slot >> 7, rr2 = (slot >> 2) & 31, kg = slot & 3;
        const float* Wm = (m == 0) ? Wq : (m == 1) ? Wk : (m == 2) ? Wv : Wg;
        short8 vv;
        #pragma unroll
        for (int j = 0; j < 8; ++j)
            vv[j] = (short)f2b(Wm[(kg * 8 + j) * RR + rr2]);
        *(short8*)&wreg[m * 1024 + nidx(rr2, kg * 8)] = vv;
    }
    if (t < 256) {
        const float S1 = redB[t] + redB[256 + t];
        const float S2 = redB[512 + t] + redB[768 + t];
        cv_s[t] = (S2 - S1 * S1 * (1.f / 64.f)) * (1.f / 63.f);
    }
    __syncthreads();

    // ================= P3: [w0-7] S5 MFMA (QG / KV pairs) -> qgkv   [w8-15] W1 partials
    if (w < 8) {
        const int ct = w >> 1, pair = w & 1;
        const int mA = pair ? 1 : 0;   // K or Q  (l2-normalized)
        const int mB = pair ? 2 : 3;   // V or G
        const int arow = ct * 16 + (lane & 15);
        const int ksub = lane >> 4;
        const short8 a = *(const short8*)&lowbuf[arow * 32 + ((ksub ^ ((arow >> 1) & 3)) << 3)];
        f32x4 aA0 = {0,0,0,0}, aA1 = {0,0,0,0}, aB0 = {0,0,0,0}, aB1 = {0,0,0,0};
        {
            const int br0 = (lane & 15), br1 = 16 + (lane & 15);
            const short8 bA0 = *(const short8*)&wreg[mA * 1024 + br0 * 32 + ((ksub ^ ((br0 >> 1) & 3)) << 3)];
            const short8 bA1 = *(const short8*)&wreg[mA * 1024 + br1 * 32 + ((ksub ^ ((br1 >> 1) & 3)) << 3)];
            const short8 bB0 = *(const short8*)&wreg[mB * 1024 + br0 * 32 + ((ksub ^ ((br0 >> 1) & 3)) << 3)];
            const short8 bB1 = *(const short8*)&wreg[mB * 1024 + br1 * 32 + ((ksub ^ ((br1 >> 1) & 3)) << 3)];
            aA0 = __builtin_amdgcn_mfma_f32_16x16x32_bf16(a, bA0, aA0, 0, 0, 0);
            aA1 = __builtin_amdgcn_mfma_f32_16x16x32_bf16(a, bA1, aA1, 0, 0, 0);
            aB0 = __builtin_amdgcn_mfma_f32_16x16x32_bf16(a, bB0, aB0, 0, 0, 0);
            aB1 = __builtin_amdgcn_mfma_f32_16x16x32_bf16(a, bB1, aB1, 0, 0, 0);
        }
        // l2norm of the A-matrix rows (over all 32 cols = 16 lanes x 2 tiles)
        float qs[4];
        #pragma unroll
        for (int i = 0; i < 4; ++i) {
            float ss = aA0[i] * aA0[i] + aA1[i] * aA1[i];
            ss += __shfl_xor(ss, 1, 64);
            ss += __shfl_xor(ss, 2, 64);
            ss += __shfl_xor(ss, 4, 64);
            ss += __shfl_xor(ss, 8, 64);
            qs[i] = 1.f / fmaxf(sqrtf(ss), 1e-12f);
        }
        const int col0 = (lane & 15), col1 = 16 + (lane & 15);
        float bgv0 = 0.f, bgv1 = 0.f;
        if (pair == 0) { bgv0 = bg[col0]; bgv1 = bg[col1]; }
        #pragma unroll
        for (int i = 0; i < 4; ++i) {
            const int c = ct * 16 + (lane >> 4) * 4 + i;
            float b0 = aB0[i], b1v = aB1[i];
            if (pair == 0) {
                b0  = 1.f / (1.f + expf(-(b0 + bgv0)));
                b1v = 1.f / (1.f + expf(-(b1v + bgv1)));
            }
            qgkv[pair * 2048 + c * 32 + col0] = (short)f2b(aA0[i] * qs[i] * b0);
            qgkv[pair * 2048 + c * 32 + col1] = (short)f2b(aA1[i] * qs[i] * b1v);
        }
    } else {
        const int idx = t - 512;
        const int j = idx & 63, dg = idx >> 6;
        float s = 0.f;
        #pragma unroll 8
        for (int i = 0; i < 32; ++i) {
            const int d = dg * 32 + i;
            s += cv_s[d] * W1[d * 64 + j];
        }
        redA[dg * 64 + j] = s;   // red3
    }
    __syncthreads();

    // ================= P4: hid gelu ; gf partials ; stage Wu^T
    if (t < 64) {
        float s = b1[t];
        #pragma unroll
        for (int g = 0; g < 8; ++g) s += redA[g * 64 + t];
        hid_s[t] = 0.5f * s * (1.f + erff(s * 0.70710678118654752f));
    }
    if (t >= 256 && t < 512) {
        const int idx = t - 256;
        const int r = idx & 31, g = idx >> 5;
        float s = 0.f;
        #pragma unroll
        for (int i = 0; i < 8; ++i)
            s += b2f((unsigned short)qgkv[2048 + (g * 8 + i) * 32 + r]);
        redA[512 + g * 32 + r] = s;   // red1
    }
    {   // Wu^T[d][k] bf16 swizzled (overwrites Wqkvg region)
        const int d = t & 255, kg = t >> 8;
        short8 vv;
        #pragma unroll
        for (int j = 0; j < 8; ++j)
            vv[j] = (short)f2b(Wu[(kg * 8 + j) * DD + d]);
        *(short8*)&wreg[nidx(d, kg * 8)] = vv;
    }
    __syncthreads();

    // ================= P5: W2 partials ; Abuf = qg * gf -> lowbuf
    {
        const int d = t & 255, jg = t >> 8;
        float s = 0.f;
        #pragma unroll
        for (int i = 0; i < 16; ++i) {
            const int j = jg * 16 + i;
            s += hid_s[j] * W2[j * DD + d];
        }
        redB[jg * 256 + d] = s;   // red2
    }
    {
        const int r = t & 31, c0 = t >> 5, c1 = (t >> 5) + 32;
        float gf = 0.f;
        #pragma unroll
        for (int g = 0; g < 8; ++g) gf += redA[512 + g * 32 + r];
        lowbuf[nidx(c0, r)] = (short)f2b(b2f((unsigned short)qgkv[c0 * 32 + r]) * gf);
        lowbuf[nidx(c1, r)] = (short)f2b(b2f((unsigned short)qgkv[c1 * 32 + r]) * gf);
    }
    __syncthreads();

    // ================= P6: gate finalize
    if (t < 256) {
        const float s = redB[t] + redB[256 + t] + redB[512 + t] + redB[768 + t] + b2[t];
        gate_s[t] = 1.f / (1.f + expf(-s));
    }
    __syncthreads();

    // ================= P7: S8 MFMA (Abuf @ Wu) + residual + store
    {
        const int ct = w & 3, dg = w >> 2;
        const int arow = ct * 16 + (lane & 15);
        const int ksub = lane >> 4;
        const short8 a = *(const short8*)&lowbuf[arow * 32 + ((ksub ^ ((arow >> 1) & 3)) << 3)];
        #pragma unroll
        for (int j = 0; j < 4; ++j) {
            const int dt = dg * 4 + j;
            const int col = dt * 16 + (lane & 15);
            const short8 bf = *(const short8*)&wreg[col * 32 + ((ksub ^ ((col >> 1) & 3)) << 3)];
            f32x4 acc = {0.f, 0.f, 0.f, 0.f};
            acc = __builtin_amdgcn_mfma_f32_16x16x32_bf16(a, bf, acc, 0, 0, 0);
            const float gt = gate_s[col];
            const float buv = bu[col];
            #pragma unroll
            for (int i = 0; i < 4; ++i) {
                const int c = ct * 16 + (lane >> 4) * 4 + i;
                const size_t off = rowbase + (size_t)c * (PB * DD) + col;
                out[off] = x[off] + gt * (acc[i] + buv);
            }
        }
    }
}

extern "C" void kernel_launch(void* const* d_in, const int* in_sizes, int n_in,
                              void* d_out, int out_size, void* d_ws, size_t ws_size,
                              hipStream_t stream) {
    (void)in_sizes; (void)n_in; (void)out_size; (void)d_ws; (void)ws_size;
    const float* x    = (const float*)d_in[0];
    const float* ln_g = (const float*)d_in[1];
    const float* ln_b = (const float*)d_in[2];
    const float* Wd   = (const float*)d_in[3];
    const float* bd   = (const float*)d_in[4];
    const float* Wq   = (const float*)d_in[5];
    const float* Wk   = (const float*)d_in[6];
    const float* Wv   = (const float*)d_in[7];
    const float* Wg   = (const float*)d_in[8];
    const float* bg   = (const float*)d_in[9];
    const float* Wu   = (const float*)d_in[10];
    const float* bu   = (const float*)d_in[11];
    const float* W1   = (const float*)d_in[12];
    const float* b1   = (const float*)d_in[13];
    const float* W2   = (const float*)d_in[14];
    const float* b2   = (const float*)d_in[15];
    float* out = (float*)d_out;

    hydra_kernel<<<dim3(32 * PB), dim3(NT), 0, stream>>>(
        x, ln_g, ln_b, Wd, bd, Wq, Wk, Wv, Wg, bg, Wu, bu, W1, b1, W2, b2, out);
}

// Round 5
// 166.232 us; speedup vs baseline: 2.8810x; 1.0390x over previous
//
#include <hip/hip_runtime.h>

#define DD 256
#define RR 32
#define CC 64
#define PB 96
#define NT 1024

typedef __attribute__((ext_vector_type(8))) short short8;
typedef __attribute__((ext_vector_type(4))) float f32x4;

__device__ __forceinline__ unsigned short f2b(float f) {
    union { float f; unsigned u; } v; v.f = f;
    unsigned r = v.u + 0x7fffu + ((v.u >> 16) & 1u);
    return (unsigned short)(r >> 16);
}
__device__ __forceinline__ float b2f(unsigned short s) {
    union { unsigned u; float f; } v; v.u = ((unsigned)s) << 16;
    return v.f;
}

// [64][256] bf16, 8-elem-block XOR swizzle by (row&7)
__device__ __forceinline__ int hidx(int c, int d) {
    return c * 256 + ((((d >> 3) ^ (c & 7)) << 3) | (d & 7));
}
// [*][32] bf16, 8-elem-block XOR swizzle by ((row>>1)&3)
__device__ __forceinline__ int nidx(int row, int k) {
    return row * 32 + ((((k >> 3) ^ ((row >> 1) & 3)) << 3) | (k & 7));
}

__global__ __launch_bounds__(NT, 8)
void hydra_kernel(const float* __restrict__ x,
                  const float* __restrict__ ln_g, const float* __restrict__ ln_b,
                  const float* __restrict__ Wd, const float* __restrict__ bd,
                  const float* __restrict__ Wq, const float* __restrict__ Wk,
                  const float* __restrict__ Wv, const float* __restrict__ Wg,
                  const float* __restrict__ bg,
                  const float* __restrict__ Wu, const float* __restrict__ bu,
                  const float* __restrict__ W1, const float* __restrict__ b1,
                  const float* __restrict__ W2, const float* __restrict__ b2,
                  float* __restrict__ out)
{
    __shared__ short hbf[CC * DD];          // 32 KB  h tile bf16 (swizzled) -> later: mixed bf16
    __shared__ short wreg[RR * DD];         // 16 KB  gWd^T -> Wqkvg^T -> Wu^T
    __shared__ short lowbuf[CC * RR];       // 4 KB   hlow bf16 -> Abuf bf16 (swizzled [64][32])
    __shared__ short qgkv[2 * CC * RR];     // 8 KB   qg | kv, linear [c][r]
    __shared__ float redA[2048];            // 8 KB   lnfold(P0-P1) | W1 partials [8][64]@0, gf [8][32]@512
    __shared__ float redB[2048];            // 8 KB   chanvar(P1-P2) | W2 partials [4][256]@0
    __shared__ float mu_s[CC], rstd_s[CC];
    __shared__ float cv_s[DD], gate_s[DD];
    __shared__ float hid_s[64];
    __shared__ float ln_a[RR], ln_bv[RR];

    const int t    = threadIdx.x;
    const int lane = t & 63;
    const int w    = t >> 6;
    const int bp   = blockIdx.x;
    const int b    = bp / PB;
    const int p    = bp - b * PB;
    const size_t rowbase = (size_t)(b * CC) * PB * DD + (size_t)p * DD;

    // ================= P0: load x -> hbf bf16 swizzled + LN stats; stage gWd^T + lnfold partials
    #pragma unroll
    for (int i = 0; i < 4; ++i) {
        const int c = w * 4 + i;
        const float4 v = *(const float4*)(x + rowbase + (size_t)c * (PB * DD) + 4 * lane);
        float s1 = v.x + v.y + v.z + v.w;
        float s2 = v.x * v.x + v.y * v.y + v.z * v.z + v.w * v.w;
        #pragma unroll
        for (int off = 32; off; off >>= 1) {
            s1 += __shfl_xor(s1, off, 64);
            s2 += __shfl_xor(s2, off, 64);
        }
        if (lane == 0) {
            const float mu = s1 * (1.f / 256.f);
            mu_s[c]   = mu;
            rstd_s[c] = rsqrtf(s2 * (1.f / 256.f) - mu * mu + 1e-5f);
        }
        ushort4 pk;
        pk.x = f2b(v.x); pk.y = f2b(v.y); pk.z = f2b(v.z); pk.w = f2b(v.w);
        *(ushort4*)&hbf[hidx(c, 4 * lane)] = pk;
    }
    {   // stage gWd^T[r][d] bf16 swizzled; lnfold partials
        const int r = t >> 5, dblk = t & 31;
        short8 vv;
        float sa = 0.f, sb = 0.f;
        #pragma unroll
        for (int j = 0; j < 8; ++j) {
            const int d = dblk * 8 + j;
            const float wd = Wd[d * RR + r];
            const float g  = ln_g[d];
            vv[j] = (short)f2b(g * wd);
            sa += g * wd;
            sb += ln_b[d] * wd;
        }
        *(short8*)&wreg[r * 256 + ((dblk ^ (r & 7)) << 3)] = vv;
        redA[r * 32 + dblk]        = sa;
        redA[1024 + r * 32 + dblk] = sb;
    }
    __syncthreads();

    // ================= P1: [w0-7] S3 MFMA (h @ gWd)   [w8-15] chan_var partials (vectorized) + lnfold finalize
    f32x4 s3acc = {0.f, 0.f, 0.f, 0.f};
    if (w < 8) {
        const int ct = w >> 1, rt = w & 1;
        const int arow = ct * 16 + (lane & 15);
        const int brow = rt * 16 + (lane & 15);
        const int ksub = lane >> 4;
        #pragma unroll
        for (int step = 0; step < 8; ++step) {
            const int kb = step * 4 + ksub;
            const short8 a  = *(const short8*)&hbf[arow * 256 + ((kb ^ (arow & 7)) << 3)];
            const short8 bf = *(const short8*)&wreg[brow * 256 + ((kb ^ (brow & 7)) << 3)];
            s3acc = __builtin_amdgcn_mfma_f32_16x16x32_bf16(a, bf, s3acc, 0, 0, 0);
        }
    } else {
        const int idx = t - 512;                 // 0..511
        const int dp  = idx & 127;               // d-pair index
        const int rg  = idx >> 7;                // 4 row-groups of 16
        const int d0  = dp * 2;
        float s1a = 0.f, s1b = 0.f, s2a = 0.f, s2b = 0.f;
        #pragma unroll 4
        for (int i = 0; i < 16; ++i) {
            const int c = rg * 16 + i;
            const ushort2 u = *(const ushort2*)&hbf[hidx(c, d0)];
            const float va = b2f(u.x), vb = b2f(u.y);
            s1a += va; s2a += va * va;
            s1b += vb; s2b += vb * vb;
        }
        *(float2*)&redB[rg * 256 + d0]        = make_float2(s1a, s1b);
        *(float2*)&redB[1024 + rg * 256 + d0] = make_float2(s2a, s2b);
        if (idx < 64) {
            const int r = idx & 31, which = idx >> 5;
            float s = 0.f;
            for (int g = 0; g < 32; ++g) s += redA[which * 1024 + r * 32 + g];
            if (which == 0) ln_a[r] = s;
            else            ln_bv[r] = s + bd[r];
        }
    }
    __syncthreads();

    // ================= P2: [w0-7] S3 epilogue -> lowbuf   [w8-15] stage Wqkvg^T ; cv finalize
    if (w < 8) {
        const int ct = w >> 1, rt = w & 1;
        const int col = rt * 16 + (lane & 15);
        const float la = ln_a[col], lb = ln_bv[col];
        #pragma unroll
        for (int i = 0; i < 4; ++i) {
            const int c = ct * 16 + (lane >> 4) * 4 + i;
            const float rs = rstd_s[c];
            const float hl = rs * s3acc[i] - rs * mu_s[c] * la + lb;
            lowbuf[nidx(c, col)] = (short)f2b(hl);
        }
    } else {
        const int slot = t - 512;
        const int m = slot >> 7, rr2 = (slot >> 2) & 31, kg = slot & 3;
        const float* Wm = (m == 0) ? Wq : (m == 1) ? Wk : (m == 2) ? Wv : Wg;
        short8 vv;
        #pragma unroll
        for (int j = 0; j < 8; ++j)
            vv[j] = (short)f2b(Wm[(kg * 8 + j) * RR + rr2]);
        *(short8*)&wreg[m * 1024 + nidx(rr2, kg * 8)] = vv;
    }
    if (t < 256) {
        const float S1 = redB[t] + redB[256 + t] + redB[512 + t] + redB[768 + t];
        const float S2 = redB[1024 + t] + redB[1280 + t] + redB[1536 + t] + redB[1792 + t];
        cv_s[t] = (S2 - S1 * S1 * (1.f / 64.f)) * (1.f / 63.f);
    }
    __syncthreads();

    // ================= P3: [w0-7] S5 MFMA (QG / KV) -> qgkv   [w8-15] W1 partials
    if (w < 8) {
        const int ct = w >> 1, pair = w & 1;
        const int mA = pair ? 1 : 0;   // K or Q (l2-normalized)
        const int mB = pair ? 2 : 3;   // V or G
        const int arow = ct * 16 + (lane & 15);
        const int ksub = lane >> 4;
        const short8 a = *(const short8*)&lowbuf[arow * 32 + ((ksub ^ ((arow >> 1) & 3)) << 3)];
        f32x4 aA0 = {0,0,0,0}, aA1 = {0,0,0,0}, aB0 = {0,0,0,0}, aB1 = {0,0,0,0};
        {
            const int br0 = (lane & 15), br1 = 16 + (lane & 15);
            const short8 bA0 = *(const short8*)&wreg[mA * 1024 + br0 * 32 + ((ksub ^ ((br0 >> 1) & 3)) << 3)];
            const short8 bA1 = *(const short8*)&wreg[mA * 1024 + br1 * 32 + ((ksub ^ ((br1 >> 1) & 3)) << 3)];
            const short8 bB0 = *(const short8*)&wreg[mB * 1024 + br0 * 32 + ((ksub ^ ((br0 >> 1) & 3)) << 3)];
            const short8 bB1 = *(const short8*)&wreg[mB * 1024 + br1 * 32 + ((ksub ^ ((br1 >> 1) & 3)) << 3)];
            aA0 = __builtin_amdgcn_mfma_f32_16x16x32_bf16(a, bA0, aA0, 0, 0, 0);
            aA1 = __builtin_amdgcn_mfma_f32_16x16x32_bf16(a, bA1, aA1, 0, 0, 0);
            aB0 = __builtin_amdgcn_mfma_f32_16x16x32_bf16(a, bB0, aB0, 0, 0, 0);
            aB1 = __builtin_amdgcn_mfma_f32_16x16x32_bf16(a, bB1, aB1, 0, 0, 0);
        }
        float qs[4];
        #pragma unroll
        for (int i = 0; i < 4; ++i) {
            float ss = aA0[i] * aA0[i] + aA1[i] * aA1[i];
            ss += __shfl_xor(ss, 1, 64);
            ss += __shfl_xor(ss, 2, 64);
            ss += __shfl_xor(ss, 4, 64);
            ss += __shfl_xor(ss, 8, 64);
            qs[i] = 1.f / fmaxf(sqrtf(ss), 1e-12f);
        }
        const int col0 = (lane & 15), col1 = 16 + (lane & 15);
        float bgv0 = 0.f, bgv1 = 0.f;
        if (pair == 0) { bgv0 = bg[col0]; bgv1 = bg[col1]; }
        #pragma unroll
        for (int i = 0; i < 4; ++i) {
            const int c = ct * 16 + (lane >> 4) * 4 + i;
            float b0 = aB0[i], b1v = aB1[i];
            if (pair == 0) {
                b0  = 1.f / (1.f + __expf(-(b0 + bgv0)));
                b1v = 1.f / (1.f + __expf(-(b1v + bgv1)));
            }
            qgkv[pair * 2048 + c * 32 + col0] = (short)f2b(aA0[i] * qs[i] * b0);
            qgkv[pair * 2048 + c * 32 + col1] = (short)f2b(aA1[i] * qs[i] * b1v);
        }
    } else {
        const int idx = t - 512;
        const int j = idx & 63, dg = idx >> 6;
        float s = 0.f;
        #pragma unroll 8
        for (int i = 0; i < 32; ++i) {
            const int d = dg * 32 + i;
            s += cv_s[d] * W1[d * 64 + j];
        }
        redA[dg * 64 + j] = s;
    }
    __syncthreads();

    // ================= P4: hid gelu ; gf partials ; stage Wu^T
    if (t < 64) {
        float s = b1[t];
        #pragma unroll
        for (int g = 0; g < 8; ++g) s += redA[g * 64 + t];
        hid_s[t] = 0.5f * s * (1.f + erff(s * 0.70710678118654752f));
    }
    if (t >= 256 && t < 512) {
        const int idx = t - 256;
        const int r = idx & 31, g = idx >> 5;
        float s = 0.f;
        #pragma unroll
        for (int i = 0; i < 8; ++i)
            s += b2f((unsigned short)qgkv[2048 + (g * 8 + i) * 32 + r]);
        redA[512 + g * 32 + r] = s;
    }
    {   // Wu^T[d][k] bf16 swizzled
        const int d = t & 255, kg = t >> 8;
        short8 vv;
        #pragma unroll
        for (int j = 0; j < 8; ++j)
            vv[j] = (short)f2b(Wu[(kg * 8 + j) * DD + d]);
        *(short8*)&wreg[nidx(d, kg * 8)] = vv;
    }
    __syncthreads();

    // ================= P5: W2 partials ; Abuf = qg * gf -> lowbuf
    {
        const int d = t & 255, jg = t >> 8;
        float s = 0.f;
        #pragma unroll
        for (int i = 0; i < 16; ++i) {
            const int j = jg * 16 + i;
            s += hid_s[j] * W2[j * DD + d];
        }
        redB[jg * 256 + d] = s;
    }
    {
        const int r = t & 31, c0 = t >> 5, c1 = (t >> 5) + 32;
        float gf = 0.f;
        #pragma unroll
        for (int g = 0; g < 8; ++g) gf += redA[512 + g * 32 + r];
        lowbuf[nidx(c0, r)] = (short)f2b(b2f((unsigned short)qgkv[c0 * 32 + r]) * gf);
        lowbuf[nidx(c1, r)] = (short)f2b(b2f((unsigned short)qgkv[c1 * 32 + r]) * gf);
    }
    __syncthreads();

    // ================= P6: S8 MFMA (Abuf @ Wu) -> mixed bf16 into hbf ; gate finalize
    {
        const int ct = w & 3, dg = w >> 2;
        const int arow = ct * 16 + (lane & 15);
        const int ksub = lane >> 4;
        const short8 a = *(const short8*)&lowbuf[arow * 32 + ((ksub ^ ((arow >> 1) & 3)) << 3)];
        #pragma unroll
        for (int j = 0; j < 4; ++j) {
            const int dt = dg * 4 + j;
            const int col = dt * 16 + (lane & 15);
            const short8 bf = *(const short8*)&wreg[col * 32 + ((ksub ^ ((col >> 1) & 3)) << 3)];
            f32x4 acc = {0.f, 0.f, 0.f, 0.f};
            acc = __builtin_amdgcn_mfma_f32_16x16x32_bf16(a, bf, acc, 0, 0, 0);
            #pragma unroll
            for (int i = 0; i < 4; ++i) {
                const int c = ct * 16 + (lane >> 4) * 4 + i;
                hbf[hidx(c, col)] = (short)f2b(acc[i]);
            }
        }
    }
    if (t < 256) {
        const float s = redB[t] + redB[256 + t] + redB[512 + t] + redB[768 + t] + b2[t];
        gate_s[t] = 1.f / (1.f + __expf(-s));
    }
    __syncthreads();

    // ================= P7: coalesced residual sweep: out = x + gate*(mixed + bu)
    #pragma unroll
    for (int i = 0; i < 4; ++i) {
        const int c = w * 4 + i;
        const size_t off = rowbase + (size_t)c * (PB * DD) + 4 * lane;
        const float4 xv = *(const float4*)(x + off);
        const ushort4 m = *(const ushort4*)&hbf[hidx(c, 4 * lane)];
        const float4 g4 = *(const float4*)&gate_s[4 * lane];
        const float4 bu4 = *(const float4*)(bu + 4 * lane);
        float4 o;
        o.x = xv.x + g4.x * (b2f(m.x) + bu4.x);
        o.y = xv.y + g4.y * (b2f(m.y) + bu4.y);
        o.z = xv.z + g4.z * (b2f(m.z) + bu4.z);
        o.w = xv.w + g4.w * (b2f(m.w) + bu4.w);
        *(float4*)(out + off) = o;
    }
}

extern "C" void kernel_launch(void* const* d_in, const int* in_sizes, int n_in,
                              void* d_out, int out_size, void* d_ws, size_t ws_size,
                              hipStream_t stream) {
    (void)in_sizes; (void)n_in; (void)out_size; (void)d_ws; (void)ws_size;
    const float* x    = (const float*)d_in[0];
    const float* ln_g = (const float*)d_in[1];
    const float* ln_b = (const float*)d_in[2];
    const float* Wd   = (const float*)d_in[3];
    const float* bd   = (const float*)d_in[4];
    const float* Wq   = (const float*)d_in[5];
    const float* Wk   = (const float*)d_in[6];
    const float* Wv   = (const float*)d_in[7];
    const float* Wg   = (const float*)d_in[8];
    const float* bg   = (const float*)d_in[9];
    const float* Wu   = (const float*)d_in[10];
    const float* bu   = (const float*)d_in[11];
    const float* W1   = (const float*)d_in[12];
    const float* b1   = (const float*)d_in[13];
    const float* W2   = (const float*)d_in[14];
    const float* b2   = (const float*)d_in[15];
    float* out = (float*)d_out;

    hydra_kernel<<<dim3(32 * PB), dim3(NT), 0, stream>>>(
        x, ln_g, ln_b, Wd, bd, Wq, Wk, Wv, Wg, bg, Wu, bu, W1, b1, W2, b2, out);
}

// Round 6
// 139.737 us; speedup vs baseline: 3.4273x; 1.1896x over previous
//
#include <hip/hip_runtime.h>

#define DD 256
#define RR 32
#define CC 64
#define PB 96
#define NT 1024

typedef __attribute__((ext_vector_type(8))) short short8;
typedef __attribute__((ext_vector_type(4))) float f32x4;

__device__ __forceinline__ unsigned short f2b(float f) {
    union { float f; unsigned u; } v; v.f = f;
    unsigned r = v.u + 0x7fffu + ((v.u >> 16) & 1u);
    return (unsigned short)(r >> 16);
}
__device__ __forceinline__ float b2f(unsigned short s) {
    union { unsigned u; float f; } v; v.u = ((unsigned)s) << 16;
    return v.f;
}

// [64][256] bf16, 8-elem-block XOR swizzle by (row&7)
__device__ __forceinline__ int hidx(int c, int d) {
    return c * 256 + ((((d >> 3) ^ (c & 7)) << 3) | (d & 7));
}
// [*][32] bf16, 8-elem-block XOR swizzle by ((row>>1)&3)
__device__ __forceinline__ int nidx(int row, int k) {
    return row * 32 + ((((k >> 3) ^ ((row >> 1) & 3)) << 3) | (k & 7));
}

// ================= prep kernel: bake pre-swizzled bf16 weight images into ws =================
__global__ __launch_bounds__(1024, 1)
void prep_kernel(const float* __restrict__ ln_g, const float* __restrict__ ln_b,
                 const float* __restrict__ Wd, const float* __restrict__ bd,
                 const float* __restrict__ Wq, const float* __restrict__ Wk,
                 const float* __restrict__ Wv, const float* __restrict__ Wg,
                 const float* __restrict__ Wu,
                 short* __restrict__ wsWd, short* __restrict__ wsQKVG,
                 short* __restrict__ wsWu, float* __restrict__ wsLN)
{
    __shared__ float redp[2048];
    const int t = threadIdx.x;
    {   // gWd^T image: [r*256 + ((dblk^(r&7))<<3) + j] = bf16(gamma[d]*Wd[d][r]), d=dblk*8+j
        const int r = t >> 5, dblk = t & 31;
        short8 vv;
        float sa = 0.f, sb = 0.f;
        #pragma unroll
        for (int j = 0; j < 8; ++j) {
            const int d = dblk * 8 + j;
            const float wd = Wd[d * RR + r];
            const float g  = ln_g[d];
            vv[j] = (short)f2b(g * wd);
            sa += g * wd;
            sb += ln_b[d] * wd;
        }
        *(short8*)&wsWd[r * 256 + ((dblk ^ (r & 7)) << 3)] = vv;
        redp[r * 32 + dblk]        = sa;
        redp[1024 + r * 32 + dblk] = sb;
    }
    if (t < 512) {  // Wqkvg^T images, m in {Q,K,V,G}
        const int m = t >> 7, rr2 = (t >> 2) & 31, kg = t & 3;
        const float* Wm = (m == 0) ? Wq : (m == 1) ? Wk : (m == 2) ? Wv : Wg;
        short8 vv;
        #pragma unroll
        for (int j = 0; j < 8; ++j)
            vv[j] = (short)f2b(Wm[(kg * 8 + j) * RR + rr2]);
        *(short8*)&wsQKVG[m * 1024 + rr2 * 32 + ((kg ^ ((rr2 >> 1) & 3)) << 3)] = vv;
    }
    {   // Wu^T image: [d*32 + ((kg^((d>>1)&3))<<3)+j] = bf16(Wu[kg*8+j][d])
        const int d = t & 255, kg = t >> 8;
        short8 vv;
        #pragma unroll
        for (int j = 0; j < 8; ++j)
            vv[j] = (short)f2b(Wu[(kg * 8 + j) * DD + d]);
        *(short8*)&wsWu[d * 32 + ((kg ^ ((d >> 1) & 3)) << 3)] = vv;
    }
    __syncthreads();
    if (t < 32) {
        float s = 0.f;
        #pragma unroll
        for (int g = 0; g < 32; ++g) s += redp[t * 32 + g];
        wsLN[t] = s;                       // ln_a
    } else if (t < 64) {
        const int r = t - 32;
        float s = 0.f;
        #pragma unroll
        for (int g = 0; g < 32; ++g) s += redp[1024 + r * 32 + g];
        wsLN[t] = s + bd[r];               // ln_bv
    }
}

// ================= main kernel =================
__global__ __launch_bounds__(NT, 8)
void hydra_kernel(const float* __restrict__ x,
                  const short* __restrict__ wsWd, const short* __restrict__ wsQKVG,
                  const short* __restrict__ wsWu, const float* __restrict__ wsLN,
                  const float* __restrict__ bg,
                  const float* __restrict__ bu,
                  const float* __restrict__ W1, const float* __restrict__ b1,
                  const float* __restrict__ W2, const float* __restrict__ b2,
                  float* __restrict__ out)
{
    __shared__ short hbf[CC * DD];      // 32 KB h tile bf16 swizzled -> later mixed bf16
    __shared__ short wreg[RR * DD / 2]; // 16 KB: gWd^T (P0-P1) -> qkvg (P2-P3) -> Wu^T (P4-P6)
    __shared__ short qg[CC * RR];       // 4 KB  Q_n*G bf16 [c][r] linear
    __shared__ short lowbuf[CC * RR];   // 4 KB  hlow -> Abuf (swizzled nidx)
    __shared__ float redA[1024];        // 4 KB  W1 partials [8][64]@0 ; gf [8][32]@512
    __shared__ float redB[2048];        // 8 KB  chanvar (P0-P2) -> kv fp32 [c][r] (P3-P4) -> W2 partials (P5)
    __shared__ float mu_s[CC], rstd_s[CC];
    __shared__ float cv_s[DD], gate_s[DD];
    __shared__ float hid_s[64];
    __shared__ float ln_a[RR], ln_bv[RR];

    const int t    = threadIdx.x;
    const int lane = t & 63;
    const int w    = t >> 6;
    const int bp   = blockIdx.x;
    const int b    = bp / PB;
    const int p    = bp - b * PB;
    const size_t rowbase = (size_t)(b * CC) * PB * DD + (size_t)p * DD;

    // ---- P0: load x -> hbf bf16 swizzled + LN stats ; copy gWd^T + ln vectors from ws ----
    #pragma unroll
    for (int i = 0; i < 4; ++i) {
        const int c = w * 4 + i;
        const float4 v = *(const float4*)(x + rowbase + (size_t)c * (PB * DD) + 4 * lane);
        float s1 = v.x + v.y + v.z + v.w;
        float s2 = v.x * v.x + v.y * v.y + v.z * v.z + v.w * v.w;
        #pragma unroll
        for (int off = 32; off; off >>= 1) {
            s1 += __shfl_xor(s1, off, 64);
            s2 += __shfl_xor(s2, off, 64);
        }
        if (lane == 0) {
            const float mu = s1 * (1.f / 256.f);
            mu_s[c]   = mu;
            rstd_s[c] = rsqrtf(s2 * (1.f / 256.f) - mu * mu + 1e-5f);
        }
        ushort4 pk;
        pk.x = f2b(v.x); pk.y = f2b(v.y); pk.z = f2b(v.z); pk.w = f2b(v.w);
        *(ushort4*)&hbf[hidx(c, 4 * lane)] = pk;
    }
    *(short8*)&wreg[t * 8] = *(const short8*)&wsWd[t * 8];
    if (t < 32)              ln_a[t]       = wsLN[t];
    else if (t < 64)         ln_bv[t - 32] = wsLN[t];
    __syncthreads();

    // ---- P1: [w0-7] S3 MFMA (h @ gWd)   [w8-15] chan_var partials ----
    f32x4 s3acc = {0.f, 0.f, 0.f, 0.f};
    if (w < 8) {
        const int ct = w >> 1, rt = w & 1;
        const int arow = ct * 16 + (lane & 15);
        const int brow = rt * 16 + (lane & 15);
        const int ksub = lane >> 4;
        #pragma unroll
        for (int step = 0; step < 8; ++step) {
            const int kb = step * 4 + ksub;
            const short8 a  = *(const short8*)&hbf[arow * 256 + ((kb ^ (arow & 7)) << 3)];
            const short8 bf = *(const short8*)&wreg[brow * 256 + ((kb ^ (brow & 7)) << 3)];
            s3acc = __builtin_amdgcn_mfma_f32_16x16x32_bf16(a, bf, s3acc, 0, 0, 0);
        }
    } else {
        const int idx = t - 512;                 // 0..511
        const int dp  = idx & 127;
        const int rg  = idx >> 7;
        const int d0  = dp * 2;
        float s1a = 0.f, s1b = 0.f, s2a = 0.f, s2b = 0.f;
        #pragma unroll 4
        for (int i = 0; i < 16; ++i) {
            const int c = rg * 16 + i;
            const ushort2 u = *(const ushort2*)&hbf[hidx(c, d0)];
            const float va = b2f(u.x), vb = b2f(u.y);
            s1a += va; s2a += va * va;
            s1b += vb; s2b += vb * vb;
        }
        *(float2*)&redB[rg * 256 + d0]        = make_float2(s1a, s1b);
        *(float2*)&redB[1024 + rg * 256 + d0] = make_float2(s2a, s2b);
    }
    __syncthreads();

    // ---- P2: [w0-7] S3 epilogue -> lowbuf   [w8-15] copy qkvg ; cv finalize ----
    if (w < 8) {
        const int ct = w >> 1, rt = w & 1;
        const int col = rt * 16 + (lane & 15);
        const float la = ln_a[col], lb = ln_bv[col];
        #pragma unroll
        for (int i = 0; i < 4; ++i) {
            const int c = ct * 16 + (lane >> 4) * 4 + i;
            const float rs = rstd_s[c];
            const float hl = rs * s3acc[i] - rs * mu_s[c] * la + lb;
            lowbuf[nidx(c, col)] = (short)f2b(hl);
        }
    } else {
        const int idx = t - 512;
        *(short8*)&wreg[idx * 8] = *(const short8*)&wsQKVG[idx * 8];
    }
    if (t < 256) {
        const float S1 = redB[t] + redB[256 + t] + redB[512 + t] + redB[768 + t];
        const float S2 = redB[1024 + t] + redB[1280 + t] + redB[1536 + t] + redB[1792 + t];
        cv_s[t] = (S2 - S1 * S1 * (1.f / 64.f)) * (1.f / 63.f);
    }
    __syncthreads();

    // ---- P3: [w0-7] S5 MFMA (QG / KV) -> qg bf16, kv fp32   [w8-15] W1 partials ----
    if (w < 8) {
        const int ct = w >> 1, pair = w & 1;
        const int mA = pair ? 1 : 0;   // K or Q (l2-normalized)
        const int mB = pair ? 2 : 3;   // V or G
        const int arow = ct * 16 + (lane & 15);
        const int ksub = lane >> 4;
        const short8 a = *(const short8*)&lowbuf[arow * 32 + ((ksub ^ ((arow >> 1) & 3)) << 3)];
        f32x4 aA0 = {0,0,0,0}, aA1 = {0,0,0,0}, aB0 = {0,0,0,0}, aB1 = {0,0,0,0};
        {
            const int br0 = (lane & 15), br1 = 16 + (lane & 15);
            const short8 bA0 = *(const short8*)&wreg[mA * 1024 + br0 * 32 + ((ksub ^ ((br0 >> 1) & 3)) << 3)];
            const short8 bA1 = *(const short8*)&wreg[mA * 1024 + br1 * 32 + ((ksub ^ ((br1 >> 1) & 3)) << 3)];
            const short8 bB0 = *(const short8*)&wreg[mB * 1024 + br0 * 32 + ((ksub ^ ((br0 >> 1) & 3)) << 3)];
            const short8 bB1 = *(const short8*)&wreg[mB * 1024 + br1 * 32 + ((ksub ^ ((br1 >> 1) & 3)) << 3)];
            aA0 = __builtin_amdgcn_mfma_f32_16x16x32_bf16(a, bA0, aA0, 0, 0, 0);
            aA1 = __builtin_amdgcn_mfma_f32_16x16x32_bf16(a, bA1, aA1, 0, 0, 0);
            aB0 = __builtin_amdgcn_mfma_f32_16x16x32_bf16(a, bB0, aB0, 0, 0, 0);
            aB1 = __builtin_amdgcn_mfma_f32_16x16x32_bf16(a, bB1, aB1, 0, 0, 0);
        }
        float qs[4];
        #pragma unroll
        for (int i = 0; i < 4; ++i) {
            float ss = aA0[i] * aA0[i] + aA1[i] * aA1[i];
            ss += __shfl_xor(ss, 1, 64);
            ss += __shfl_xor(ss, 2, 64);
            ss += __shfl_xor(ss, 4, 64);
            ss += __shfl_xor(ss, 8, 64);
            qs[i] = 1.f / fmaxf(sqrtf(ss), 1e-12f);
        }
        const int col0 = (lane & 15), col1 = 16 + (lane & 15);
        if (pair == 0) {
            const float bgv0 = bg[col0], bgv1 = bg[col1];
            #pragma unroll
            for (int i = 0; i < 4; ++i) {
                const int c = ct * 16 + (lane >> 4) * 4 + i;
                const float g0 = 1.f / (1.f + __expf(-(aB0[i] + bgv0)));
                const float g1 = 1.f / (1.f + __expf(-(aB1[i] + bgv1)));
                qg[c * 32 + col0] = (short)f2b(aA0[i] * qs[i] * g0);
                qg[c * 32 + col1] = (short)f2b(aA1[i] * qs[i] * g1);
            }
        } else {
            #pragma unroll
            for (int i = 0; i < 4; ++i) {
                const int c = ct * 16 + (lane >> 4) * 4 + i;
                redB[c * 32 + col0] = aA0[i] * qs[i] * aB0[i];   // K_n * V, fp32
                redB[c * 32 + col1] = aA1[i] * qs[i] * aB1[i];
            }
        }
    } else {
        const int idx = t - 512;
        const int j = idx & 63, dg = idx >> 6;
        float s = 0.f;
        #pragma unroll 8
        for (int i = 0; i < 32; ++i) {
            const int d = dg * 32 + i;
            s += cv_s[d] * W1[d * 64 + j];
        }
        redA[dg * 64 + j] = s;
    }
    __syncthreads();

    // ---- P4: hid gelu ; gf partials (fp32 kv) ; copy Wu^T ----
    if (t < 64) {
        float s = b1[t];
        #pragma unroll
        for (int g = 0; g < 8; ++g) s += redA[g * 64 + t];
        hid_s[t] = 0.5f * s * (1.f + erff(s * 0.70710678118654752f));
    }
    if (t >= 256 && t < 512) {
        const int idx = t - 256;
        const int r = idx & 31, g = idx >> 5;
        float s = 0.f;
        #pragma unroll
        for (int i = 0; i < 8; ++i)
            s += redB[(g * 8 + i) * 32 + r];
        redA[512 + g * 32 + r] = s;
    }
    *(short8*)&wreg[t * 8] = *(const short8*)&wsWu[t * 8];
    __syncthreads();

    // ---- P5: W2 partials ; Abuf = qg * gf -> lowbuf ----
    {
        const int d = t & 255, jg = t >> 8;
        float s = 0.f;
        #pragma unroll
        for (int i = 0; i < 16; ++i) {
            const int j = jg * 16 + i;
            s += hid_s[j] * W2[j * DD + d];
        }
        redB[jg * 256 + d] = s;
    }
    if (t < 256) {
        const int r = t & 31, c0 = t >> 5, c1 = (t >> 5) + 32;
        float gf = 0.f;
        #pragma unroll
        for (int g = 0; g < 8; ++g) gf += redA[512 + g * 32 + r];
        lowbuf[nidx(c0, r)] = (short)f2b(b2f((unsigned short)qg[c0 * 32 + r]) * gf);
        lowbuf[nidx(c1, r)] = (short)f2b(b2f((unsigned short)qg[c1 * 32 + r]) * gf);
    }
    __syncthreads();

    // ---- P6: S8 MFMA (Abuf @ Wu^T) -> mixed bf16 into hbf ; gate finalize ----
    {
        const int ct = w & 3, dg = w >> 2;
        const int arow = ct * 16 + (lane & 15);
        const int ksub = lane >> 4;
        const short8 a = *(const short8*)&lowbuf[arow * 32 + ((ksub ^ ((arow >> 1) & 3)) << 3)];
        #pragma unroll
        for (int j = 0; j < 4; ++j) {
            const int dt = dg * 4 + j;
            const int col = dt * 16 + (lane & 15);
            const short8 bf = *(const short8*)&wreg[col * 32 + ((ksub ^ ((col >> 1) & 3)) << 3)];
            f32x4 acc = {0.f, 0.f, 0.f, 0.f};
            acc = __builtin_amdgcn_mfma_f32_16x16x32_bf16(a, bf, acc, 0, 0, 0);
            #pragma unroll
            for (int i = 0; i < 4; ++i) {
                const int c = ct * 16 + (lane >> 4) * 4 + i;
                hbf[hidx(c, col)] = (short)f2b(acc[i]);
            }
        }
    }
    if (t < 256) {
        const float s = redB[t] + redB[256 + t] + redB[512 + t] + redB[768 + t] + b2[t];
        gate_s[t] = 1.f / (1.f + __expf(-s));
    }
    __syncthreads();

    // ---- P7: coalesced residual sweep: out = x + gate*(mixed + bu) ----
    #pragma unroll
    for (int i = 0; i < 4; ++i) {
        const int c = w * 4 + i;
        const size_t off = rowbase + (size_t)c * (PB * DD) + 4 * lane;
        const float4 xv = *(const float4*)(x + off);
        const ushort4 m = *(const ushort4*)&hbf[hidx(c, 4 * lane)];
        const float4 g4 = *(const float4*)&gate_s[4 * lane];
        const float4 bu4 = *(const float4*)(bu + 4 * lane);
        float4 o;
        o.x = xv.x + g4.x * (b2f(m.x) + bu4.x);
        o.y = xv.y + g4.y * (b2f(m.y) + bu4.y);
        o.z = xv.z + g4.z * (b2f(m.z) + bu4.z);
        o.w = xv.w + g4.w * (b2f(m.w) + bu4.w);
        *(float4*)(out + off) = o;
    }
}

extern "C" void kernel_launch(void* const* d_in, const int* in_sizes, int n_in,
                              void* d_out, int out_size, void* d_ws, size_t ws_size,
                              hipStream_t stream) {
    (void)in_sizes; (void)n_in; (void)out_size; (void)ws_size;
    const float* x    = (const float*)d_in[0];
    const float* ln_g = (const float*)d_in[1];
    const float* ln_b = (const float*)d_in[2];
    const float* Wd   = (const float*)d_in[3];
    const float* bd   = (const float*)d_in[4];
    const float* Wq   = (const float*)d_in[5];
    const float* Wk   = (const float*)d_in[6];
    const float* Wv   = (const float*)d_in[7];
    const float* Wg   = (const float*)d_in[8];
    const float* bg   = (const float*)d_in[9];
    const float* Wu   = (const float*)d_in[10];
    const float* bu   = (const float*)d_in[11];
    const float* W1   = (const float*)d_in[12];
    const float* b1   = (const float*)d_in[13];
    const float* W2   = (const float*)d_in[14];
    const float* b2   = (const float*)d_in[15];
    float* out = (float*)d_out;

    short* wsWd   = (short*)d_ws;          // 8192 shorts
    short* wsQKVG = wsWd + 8192;           // 4096 shorts
    short* wsWu   = wsQKVG + 4096;         // 8192 shorts
    float* wsLN   = (float*)(wsWd + 20480);// 64 floats

    prep_kernel<<<dim3(1), dim3(1024), 0, stream>>>(
        ln_g, ln_b, Wd, bd, Wq, Wk, Wv, Wg, Wu, wsWd, wsQKVG, wsWu, wsLN);
    hydra_kernel<<<dim3(32 * PB), dim3(NT), 0, stream>>>(
        x, wsWd, wsQKVG, wsWu, wsLN, bg, bu, W1, b1, W2, b2, out);
}